// Round 2
// baseline (178.205 us; speedup 1.0000x reference)
//
#include <hip/hip_runtime.h>
#include <hip/hip_fp16.h>

typedef _Float16 half8 __attribute__((ext_vector_type(8)));
typedef _Float16 half4 __attribute__((ext_vector_type(4)));
typedef float f32x4 __attribute__((ext_vector_type(4)));

#define BATCH 65536
#define KD 512
#define HD 256
#define BHSZ 16777216  // BATCH * HD

// ---------------------------------------------------------------------------
__device__ __forceinline__ void gload16(const _Float16* g, _Float16* lds) {
  __builtin_amdgcn_global_load_lds((const __attribute__((address_space(1))) void*)g,
                                   (__attribute__((address_space(3))) void*)lds,
                                   16, 0, 0);
}

__device__ __forceinline__ float fast_sigmoid(float z) {
  float e = __builtin_amdgcn_exp2f(-z * 1.4426950408889634f);
  return __builtin_amdgcn_rcpf(1.0f + e);
}

__device__ __forceinline__ float fast_tanh(float z) {
  float a = __builtin_fabsf(z);
  float e = __builtin_amdgcn_exp2f(a * 2.8853900817779268f);
  float t = 1.0f - 2.0f * __builtin_amdgcn_rcpf(1.0f + e);
  return z < 0.0f ? -t : t;
}

// ---------------------------------------------------------------------------
// pack_b: Bp[N'][k] fp16 (B^T, N'-major), gate-interleaved columns:
//   N' = t*64 + g*16 + j -> logical col cl = t*16 + j, gate g (0=f,1=i,2=o,3=c)
// ---------------------------------------------------------------------------
__global__ __launch_bounds__(256) void pack_b(
    const float* __restrict__ Wf, const float* __restrict__ Uf,
    const float* __restrict__ Wi, const float* __restrict__ Ui,
    const float* __restrict__ Wo, const float* __restrict__ Uo,
    const float* __restrict__ Wc, const float* __restrict__ Uc,
    _Float16* __restrict__ Bp) {
  int idx = blockIdx.x * 256 + threadIdx.x;  // [0, 524288)
  int k = idx & 511;
  int Np = idx >> 9;
  int g = (Np >> 4) & 3;
  int cl = ((Np >> 6) << 4) | (Np & 15);
  const float* W;
  const float* U;
  switch (g) {
    case 0: W = Wf; U = Uf; break;
    case 1: W = Wi; U = Ui; break;
    case 2: W = Wo; U = Uo; break;
    default: W = Wc; U = Uc; break;
  }
  float v = (k < 256) ? W[k * 256 + cl] : U[(k - 256) * 256 + cl];
  Bp[idx] = (_Float16)v;
}

// ---------------------------------------------------------------------------
// lstm_fused: z = [x|h] @ Bp^T tile (128x128) with on-the-fly fp32->fp16
// A-staging (reg -> swizzled ds_write), double-buffered LDS, 2-phase
// prefetch, fused LSTM gate epilogue.
// grid = 4096; XCD-swizzled so each XCD owns a contiguous bm range.
// ---------------------------------------------------------------------------
__global__ __launch_bounds__(256) void lstm_fused(
    const float* __restrict__ x, const float* __restrict__ h,
    const _Float16* __restrict__ Bp, const float* __restrict__ cin,
    const float* __restrict__ bf_, const float* __restrict__ bi_,
    const float* __restrict__ bo_, const float* __restrict__ bc_,
    float* __restrict__ out) {
  __shared__ _Float16 As[2][128 * 64];
  __shared__ _Float16 Bs[2][128 * 64];

  int tid = threadIdx.x;
  int w = tid >> 6, l = tid & 63;
  int l15 = l & 15, lg = l >> 4;

  // XCD swizzle: nwg=4096, 8 XCDs, 512 blocks each. XCD x (= bid%8) gets
  // contiguous wgid chunk [x*512,(x+1)*512) -> bm in [x*64,(x+1)*64), all bn.
  int bid = blockIdx.x;
  int wgid = (bid & 7) * 512 + (bid >> 3);
  int bm = wgid >> 3, bn = wgid & 7;
  int wr = w >> 1, wc = w & 1;

  // --- B staging via global_load_lds (source-side swizzle, linear LDS dest)
  long gbOff[4];
  int ldsB[4];
#pragma unroll
  for (int i2 = 0; i2 < 4; ++i2) {
    int idx = i2 * 256 + tid;
    int row = idx >> 3, slot = idx & 7;
    int swz = slot ^ (row & 7);
    gbOff[i2] = (long)(bn * 128 + row) * 512 + swz * 8;
    ldsB[i2] = (i2 * 256 + w * 64) * 8;
  }

  // --- A reg staging: instruction j covers rows j*16+(tid>>4), 16 lanes/row,
  // each lane one float4 (16B) -> 256B contiguous per row.
  int arow = tid >> 4;   // 0..15
  int am = tid & 15;     // 16B chunk within the 64-col k-slice
  float4 aReg[8];

  f32x4 acc[4][4];
#pragma unroll
  for (int a2 = 0; a2 < 4; ++a2)
#pragma unroll
    for (int b2 = 0; b2 < 4; ++b2)
      acc[a2][b2] = (f32x4){0.f, 0.f, 0.f, 0.f};

  auto issueA = [&](int kt) {
    const float* src = (kt < 4) ? x : h;
    int ko = (kt & 3) * 64;
#pragma unroll
    for (int j = 0; j < 8; ++j) {
      long row = (long)(bm * 128 + j * 16 + arow);
      aReg[j] = *reinterpret_cast<const float4*>(src + row * 256 + ko + am * 4);
    }
  };
  auto issueB = [&](int kt, int buf) {
    int ko = kt * 64;
#pragma unroll
    for (int i2 = 0; i2 < 4; ++i2)
      gload16(Bp + gbOff[i2] + ko, &Bs[buf][0] + ldsB[i2]);
  };
  auto writeA = [&](int buf) {
#pragma unroll
    for (int j = 0; j < 8; ++j) {
      int row = j * 16 + arow;
      // fp16 row = 64 halves = 8 slots of 16B; this lane's 4 halves land at
      // slot (am>>1), half (am&1); XOR-swizzle the slot by row&7.
      int off = row * 64 + (((am >> 1) ^ (row & 7)) << 3) + ((am & 1) << 2);
      half4 o;
      o[0] = (_Float16)aReg[j].x; o[1] = (_Float16)aReg[j].y;
      o[2] = (_Float16)aReg[j].z; o[3] = (_Float16)aReg[j].w;
      *reinterpret_cast<half4*>(&As[buf][off]) = o;
    }
  };

  // Prologue: fill buffer 0.
  issueA(0);
  issueB(0, 0);
  writeA(0);
  __syncthreads();

  int buf = 0;
  for (int kt = 0; kt < 8; ++kt) {
    if (kt < 7) {
      issueA(kt + 1);
      issueB(kt + 1, buf ^ 1);
    }
#pragma unroll
    for (int kk = 0; kk < 2; ++kk) {
      half8 av[4], bv[4];
#pragma unroll
      for (int mf = 0; mf < 4; ++mf) {
        int row = wr * 64 + mf * 16 + l15;
        int swz = (kk * 4 + lg) ^ (row & 7);
        av[mf] = *reinterpret_cast<const half8*>(&As[buf][row * 64 + swz * 8]);
      }
#pragma unroll
      for (int nf = 0; nf < 4; ++nf) {
        int row = wc * 64 + nf * 16 + l15;
        int swz = (kk * 4 + lg) ^ (row & 7);
        bv[nf] = *reinterpret_cast<const half8*>(&Bs[buf][row * 64 + swz * 8]);
      }
      __builtin_amdgcn_s_setprio(1);
#pragma unroll
      for (int mf = 0; mf < 4; ++mf)
#pragma unroll
        for (int nf = 0; nf < 4; ++nf)
          acc[mf][nf] = __builtin_amdgcn_mfma_f32_16x16x32_f16(
              av[mf], bv[nf], acc[mf][nf], 0, 0, 0);
      __builtin_amdgcn_s_setprio(0);
    }
    if (kt < 7) writeA(buf ^ 1);  // vmcnt wait lands here, after the MFMAs
    __syncthreads();
    buf ^= 1;
  }

  // Epilogue: fragment nf == gate (0=f,1=i,2=o,3=c); C/D: col=lane&15,
  // row=(lane>>4)*4+reg.
  int t = bn * 2 + wc;
  int col = t * 16 + l15;  // logical column in [0,256)
  float vbf = bf_[col], vbi = bi_[col], vbo = bo_[col], vbc = bc_[col];
#pragma unroll
  for (int mf = 0; mf < 4; ++mf) {
#pragma unroll
    for (int r = 0; r < 4; ++r) {
      long row = (long)(bm * 128 + wr * 64 + mf * 16 + lg * 4 + r);
      float zf = acc[mf][0][r] + vbf;
      float zi = acc[mf][1][r] + vbi;
      float zo = acc[mf][2][r] + vbo;
      float zg = acc[mf][3][r] + vbc;
      float fg = fast_sigmoid(zf);
      float ig = fast_sigmoid(zi);
      float og = fast_sigmoid(zo);
      float gg = fast_tanh(zg);
      float cv = cin[row * 256 + col];
      float cn = cv * fg + gg * ig;
      float hn = og * fast_tanh(cn);
      out[row * 256 + col] = cn;
      out[BHSZ + row * 256 + col] = hn;
    }
  }
}

// ---------------------------------------------------------------------------
extern "C" void kernel_launch(void* const* d_in, const int* in_sizes, int n_in,
                              void* d_out, int out_size, void* d_ws, size_t ws_size,
                              hipStream_t stream) {
  const float* x  = (const float*)d_in[0];
  const float* c  = (const float*)d_in[1];
  const float* h  = (const float*)d_in[2];
  const float* Wi = (const float*)d_in[3];
  const float* Ui = (const float*)d_in[4];
  const float* bi = (const float*)d_in[5];
  const float* Wf = (const float*)d_in[6];
  const float* Uf = (const float*)d_in[7];
  const float* bf = (const float*)d_in[8];
  const float* Wc = (const float*)d_in[9];
  const float* Uc = (const float*)d_in[10];
  const float* bc = (const float*)d_in[11];
  const float* Wo = (const float*)d_in[12];
  const float* Uo = (const float*)d_in[13];
  const float* bo = (const float*)d_in[14];

  _Float16* Bp = (_Float16*)d_ws;  // 1 MB packed weights

  pack_b<<<2048, 256, 0, stream>>>(Wf, Uf, Wi, Ui, Wo, Uo, Wc, Uc, Bp);
  lstm_fused<<<4096, 256, 0, stream>>>(x, h, Bp, c, bf, bi, bo, bc,
                                       (float*)d_out);
}

// Round 3
// 173.537 us; speedup vs baseline: 1.0269x; 1.0269x over previous
//
#include <hip/hip_runtime.h>
#include <hip/hip_fp16.h>

typedef _Float16 half8 __attribute__((ext_vector_type(8)));
typedef float f32x4 __attribute__((ext_vector_type(4)));

#define BATCH 65536
#define BHSZ 16777216  // BATCH * 256

#define WAITL()  asm volatile("s_waitcnt lgkmcnt(0)" ::: "memory")
#define SBAR()   __builtin_amdgcn_s_barrier()
#define SCHEDB() __builtin_amdgcn_sched_barrier(0)

// ---------------------------------------------------------------------------
__device__ __forceinline__ void gload16(const _Float16* g, _Float16* lds) {
  __builtin_amdgcn_global_load_lds((const __attribute__((address_space(1))) void*)g,
                                   (__attribute__((address_space(3))) void*)lds,
                                   16, 0, 0);
}

__device__ __forceinline__ float fast_sigmoid(float z) {
  float e = __builtin_amdgcn_exp2f(-z * 1.4426950408889634f);
  return __builtin_amdgcn_rcpf(1.0f + e);
}

__device__ __forceinline__ float fast_tanh(float z) {
  float a = __builtin_fabsf(z);
  float e = __builtin_amdgcn_exp2f(a * 2.8853900817779268f);
  float t = 1.0f - 2.0f * __builtin_amdgcn_rcpf(1.0f + e);
  return z < 0.0f ? -t : t;
}

// ---------------------------------------------------------------------------
// pack_b: Bp[N'][k] fp16 (B^T, N'-major), gate-interleaved columns:
//   N' = t*64 + g*16 + j -> logical col cl = t*16 + j, gate g (0=f,1=i,2=o,3=c)
// ---------------------------------------------------------------------------
__global__ __launch_bounds__(256) void pack_b(
    const float* __restrict__ Wf, const float* __restrict__ Uf,
    const float* __restrict__ Wi, const float* __restrict__ Ui,
    const float* __restrict__ Wo, const float* __restrict__ Uo,
    const float* __restrict__ Wc, const float* __restrict__ Uc,
    _Float16* __restrict__ Bp) {
  int idx = blockIdx.x * 256 + threadIdx.x;  // [0, 524288)
  int k = idx & 511;
  int Np = idx >> 9;
  int g = (Np >> 4) & 3;
  int cl = ((Np >> 6) << 4) | (Np & 15);
  const float* W;
  const float* U;
  switch (g) {
    case 0: W = Wf; U = Uf; break;
    case 1: W = Wi; U = Ui; break;
    case 2: W = Wo; U = Uo; break;
    default: W = Wc; U = Uc; break;
  }
  float v = (k < 256) ? W[k * 256 + cl] : U[(k - 256) * 256 + cl];
  Bp[idx] = (_Float16)v;
}

// ---------------------------------------------------------------------------
// lstm_fused: 256x256 tile (BM=256 rows, BN'=256 gate-interleaved cols),
// BK=32, 16 K-steps, 512 threads (8 waves of 128x64, acc 8x4 frags).
// B: 4-deep LDS ring, global_load_lds staged 2 steps ahead (in flight across
//    barriers, confirmed by compiler auto-waits -- no vmcnt(0) drains).
// A: fp32->fp16 reg-staged, 2-deep LDS ring, written 1 step ahead.
// grid = 1024; bn-fastest XCD ordering for L2 A-panel sharing.
// ---------------------------------------------------------------------------
__global__ __launch_bounds__(512, 2) void lstm_fused(
    const float* __restrict__ x, const float* __restrict__ h,
    const _Float16* __restrict__ Bp, const float* __restrict__ cin,
    const float* __restrict__ bf_, const float* __restrict__ bi_,
    const float* __restrict__ bo_, const float* __restrict__ bc_,
    float* __restrict__ out) {
  __shared__ _Float16 As[2][256 * 32];  // 32 KB
  __shared__ _Float16 Bs[4][256 * 32];  // 64 KB

  int tid = threadIdx.x;
  int w = tid >> 6, l = tid & 63;
  int l15 = l & 15, lg = l >> 4;

  // XCD mapping: xcd = bid&7 owns wg [xcd*128, ..+128); within: bn fastest so
  // the 4 bn-blocks of one bm run concurrently on one XCD (A-panel in L2).
  int bid = blockIdx.x;
  int wg = (bid & 7) * 128 + (bid >> 3);
  int bm = wg >> 2, bn = wg & 3;
  int wr = w >> 2, wcn = w & 3;  // 2M x 4N wave grid

  // --- A global staging: thread -> row tid>>1, half tid&1 (16 fp32 = 64B)
  int arow = tid >> 1, ahalf = tid & 1;
  const float* aRowX = x + (long)(bm * 256 + arow) * 256 + ahalf * 16;
  const float* aRowH = h + (long)(bm * 256 + arow) * 256 + ahalf * 16;

  // A LDS write offsets (halves); 4 slots/row, swz = slot ^ ((row>>1)&3)
  int awr = (arow >> 1) & 3;
  int offW0 = arow * 32 + (((ahalf * 2 + 0) ^ awr) << 3);
  int offW1 = arow * 32 + (((ahalf * 2 + 1) ^ awr) << 3);

  // --- B staging via global_load_lds: chunk c = i*512 + w*64 + l
  int c0 = w * 64 + l;
  int brow0 = c0 >> 2, bslot = c0 & 3;
  int bswz = bslot ^ ((brow0 >> 1) & 3);
  const _Float16* bSrc0 = Bp + (long)(bn * 256 + brow0) * 512 + bswz * 8;

  // --- fragment read offsets (halves), swz = lg ^ ((row>>1)&3)
  int offA[8], offB[4];
#pragma unroll
  for (int mf = 0; mf < 8; ++mf) {
    int row = wr * 128 + mf * 16 + l15;
    offA[mf] = row * 32 + ((lg ^ ((row >> 1) & 3)) << 3);
  }
#pragma unroll
  for (int nf = 0; nf < 4; ++nf) {
    int row = wcn * 64 + nf * 16 + l15;
    offB[nf] = row * 32 + ((lg ^ ((row >> 1) & 3)) << 3);
  }

  f32x4 acc[8][4];
#pragma unroll
  for (int a2 = 0; a2 < 8; ++a2)
#pragma unroll
    for (int b2 = 0; b2 < 4; ++b2)
      acc[a2][b2] = (f32x4){0.f, 0.f, 0.f, 0.f};

  float4 rp[2][4];  // A reg ping-pong (static-indexed after unroll)

  auto issueB = [&](int tt, int ring) {
    const _Float16* s = bSrc0 + tt * 32;
#pragma unroll
    for (int i = 0; i < 2; ++i)
      gload16(s + i * 65536, &Bs[ring][0] + (i * 512 + w * 64) * 8);
  };
  auto issueA = [&](int tt, float4* r) {
    const float* base = (tt < 8) ? aRowX : aRowH;
    int ko = (tt & 7) * 32;
#pragma unroll
    for (int q = 0; q < 4; ++q)
      r[q] = *reinterpret_cast<const float4*>(base + ko + q * 4);
  };
  auto cvtWrite = [&](const float4* r, int ab) {
    half8 h0, h1;
    h0[0] = (_Float16)r[0].x; h0[1] = (_Float16)r[0].y;
    h0[2] = (_Float16)r[0].z; h0[3] = (_Float16)r[0].w;
    h0[4] = (_Float16)r[1].x; h0[5] = (_Float16)r[1].y;
    h0[6] = (_Float16)r[1].z; h0[7] = (_Float16)r[1].w;
    h1[0] = (_Float16)r[2].x; h1[1] = (_Float16)r[2].y;
    h1[2] = (_Float16)r[2].z; h1[3] = (_Float16)r[2].w;
    h1[4] = (_Float16)r[3].x; h1[5] = (_Float16)r[3].y;
    h1[6] = (_Float16)r[3].z; h1[7] = (_Float16)r[3].w;
    *reinterpret_cast<half8*>(&As[ab][offW0]) = h0;
    *reinterpret_cast<half8*>(&As[ab][offW1]) = h1;
  };

  // --- Prologue: tile 0 staged + tile 1 in flight.
  issueB(0, 0);
  SCHEDB();
  issueA(0, rp[0]);
  SCHEDB();
  cvtWrite(rp[0], 0);  // compiler auto-waits A(0); B(0) older -> also done
  issueB(1, 1);
  SCHEDB();
  issueA(1, rp[1]);  // A(1) regs: CUR for step 0
  SCHEDB();
  WAITL();
  SBAR();

#pragma unroll
  for (int t = 0; t < 16; ++t) {
    if (t < 14) {
      issueB(t + 2, (t + 2) & 3);
      SCHEDB();
      issueA(t + 2, rp[t & 1]);  // NXT = A(t+2)
      SCHEDB();
    }
    half8 av[8], bv[4];
    const _Float16* aB = &As[t & 1][0];
    const _Float16* bB = &Bs[t & 3][0];
#pragma unroll
    for (int mf = 0; mf < 8; ++mf)
      av[mf] = *reinterpret_cast<const half8*>(aB + offA[mf]);
#pragma unroll
    for (int nf = 0; nf < 4; ++nf)
      bv[nf] = *reinterpret_cast<const half8*>(bB + offB[nf]);
    WAITL();
    SCHEDB();
    __builtin_amdgcn_s_setprio(1);
#pragma unroll
    for (int mf = 0; mf < 8; ++mf)
#pragma unroll
      for (int nf = 0; nf < 4; ++nf)
        acc[mf][nf] = __builtin_amdgcn_mfma_f32_16x16x32_f16(
            av[mf], bv[nf], acc[mf][nf], 0, 0, 0);
    __builtin_amdgcn_s_setprio(0);
    SCHEDB();
    if (t < 15) {
      // auto vmcnt here covers A(t+1) regs AND (issued earlier) B(t+1)'s
      // global_load_lds -> after the barrier everyone may read Bs[(t+1)&3].
      cvtWrite(rp[(t + 1) & 1], (t + 1) & 1);
      WAITL();
      SBAR();
    }
  }

  // --- Epilogue: n-frag == gate (0=f,1=i,2=o,3=c); C/D: col=lane&15,
  // row=(lane>>4)*4+reg.
  int tcol = bn * 4 + wcn;
  int col = tcol * 16 + l15;  // logical column in [0,256)
  float vbf = bf_[col], vbi = bi_[col], vbo = bo_[col], vbc = bc_[col];
#pragma unroll
  for (int mf = 0; mf < 8; ++mf) {
#pragma unroll
    for (int r = 0; r < 4; ++r) {
      long row = (long)(bm * 256 + wr * 128 + mf * 16 + lg * 4 + r);
      float zf = acc[mf][0][r] + vbf;
      float zi = acc[mf][1][r] + vbi;
      float zo = acc[mf][2][r] + vbo;
      float zg = acc[mf][3][r] + vbc;
      float fg = fast_sigmoid(zf);
      float ig = fast_sigmoid(zi);
      float og = fast_sigmoid(zo);
      float gg = fast_tanh(zg);
      float cv = cin[row * 256 + col];
      float cn = cv * fg + gg * ig;
      float hn = og * fast_tanh(cn);
      out[row * 256 + col] = cn;
      out[BHSZ + row * 256 + col] = hn;
    }
  }
}

// ---------------------------------------------------------------------------
extern "C" void kernel_launch(void* const* d_in, const int* in_sizes, int n_in,
                              void* d_out, int out_size, void* d_ws, size_t ws_size,
                              hipStream_t stream) {
  const float* x  = (const float*)d_in[0];
  const float* c  = (const float*)d_in[1];
  const float* h  = (const float*)d_in[2];
  const float* Wi = (const float*)d_in[3];
  const float* Ui = (const float*)d_in[4];
  const float* bi = (const float*)d_in[5];
  const float* Wf = (const float*)d_in[6];
  const float* Uf = (const float*)d_in[7];
  const float* bf = (const float*)d_in[8];
  const float* Wc = (const float*)d_in[9];
  const float* Uc = (const float*)d_in[10];
  const float* bc = (const float*)d_in[11];
  const float* Wo = (const float*)d_in[12];
  const float* Uo = (const float*)d_in[13];
  const float* bo = (const float*)d_in[14];

  _Float16* Bp = (_Float16*)d_ws;  // 1 MB packed weights

  pack_b<<<2048, 256, 0, stream>>>(Wf, Uf, Wi, Ui, Wo, Uo, Wc, Uc, Bp);
  lstm_fused<<<1024, 512, 0, stream>>>(x, h, Bp, c, bf, bi, bo, bc,
                                       (float*)d_out);
}